// Round 3
// baseline (108.516 us; speedup 1.0000x reference)
//
#include <hip/hip_runtime.h>
#include <math.h>

#define BB 32
#define NN 1024
#define DD 512
#define SS 4
#define RR 64
#define OUTC 256          // SS*RR
#define NT (BB*NN)        // 32768 tokens
#define MT 32             // tokens per fused block
#define NBLK (NT/MT)      // 1024

typedef float4 f4;
typedef float f32x4 __attribute__((ext_vector_type(4)));
typedef __bf16 bf16x8 __attribute__((ext_vector_type(8)));
typedef unsigned short u16x8 __attribute__((ext_vector_type(8)));
typedef const __attribute__((address_space(1))) void GVoid;
typedef __attribute__((address_space(3))) void LVoid;

union BF8 { u16x8 u; bf16x8 b; unsigned w[4]; };

__device__ __forceinline__ float hif(float f) {
  return __uint_as_float(__float_as_uint(f) & 0xffff0000u);
}
__device__ __forceinline__ unsigned short topu(float f) {
  return (unsigned short)(__float_as_uint(f) >> 16);
}
// pack hi-16 halves of (e0,e1) into one u32. Producer/consumer both use this,
// so any within-pair ordering is consistent on A and B => MFMA dot invariant.
__device__ __forceinline__ unsigned pack2(float e0, float e1) {
  return __builtin_amdgcn_perm(__float_as_uint(e1), __float_as_uint(e0), 0x07060302u);
}

#define MFMA(a,b,c) __builtin_amdgcn_mfma_f32_16x16x32_bf16((a),(b),(c),0,0,0)

// ---------------- prep: sub -> bf16 hi/lo; Gram G_s = S_s S_s^T -> bf16 hi/lo
__global__ __launch_bounds__(256) void prep_kernel(const float* __restrict__ sub,
    unsigned short* __restrict__ subhi, unsigned short* __restrict__ sublo,
    unsigned short* __restrict__ Ghi, unsigned short* __restrict__ Glo) {
  int t = threadIdx.x, blk = blockIdx.x;
  __shared__ __align__(16) float Sl[64][36];
  if (blk < 128) {
    int i = (blk*256 + t)*4;                   // 128*256*4 = 131072 = OUTC*DD
    f4 v = *(const f4*)&sub[i];
    uint2 hh, ll;
    hh.x = pack2(v.x, v.y); hh.y = pack2(v.z, v.w);
    ll.x = pack2(v.x - hif(v.x), v.y - hif(v.y));
    ll.y = pack2(v.z - hif(v.z), v.w - hif(v.w));
    *(uint2*)&subhi[i] = hh;
    *(uint2*)&sublo[i] = ll;
    return;
  }
  int s = blk - 128;
  int lane = t & 63, w = t >> 6, l15 = lane & 15, l4 = lane >> 4;
  int row = t >> 2, seg = t & 3;               // staging: 64 rows x 4 segs of 8
  f4 r0, r1;
  f32x4 acc[4] = {{0,0,0,0},{0,0,0,0},{0,0,0,0},{0,0,0,0}};
  {
    const float* p = &sub[(size_t)(s*RR + row)*DD + seg*8];
    r0 = *(const f4*)p; r1 = *(const f4*)(p+4);
  }
  for (int kc = 0; kc < 16; ++kc) {
    __syncthreads();
    *(f4*)&Sl[row][seg*8]   = r0;
    *(f4*)&Sl[row][seg*8+4] = r1;
    __syncthreads();
    if (kc < 15) {
      const float* p = &sub[(size_t)(s*RR + row)*DD + (kc+1)*32 + seg*8];
      r0 = *(const f4*)p; r1 = *(const f4*)(p+4);
    }
    BF8 ah, al;
    {
      int ra = w*16 + l15;
      f32x4 v0 = *(const f32x4*)&Sl[ra][l4*8];
      f32x4 v1 = *(const f32x4*)&Sl[ra][l4*8+4];
      float ff[8] = {v0[0],v0[1],v0[2],v0[3],v1[0],v1[1],v1[2],v1[3]};
#pragma unroll
      for (int e = 0; e < 8; ++e) { ah.u[e] = topu(ff[e]); al.u[e] = topu(ff[e]-hif(ff[e])); }
    }
#pragma unroll
    for (int j = 0; j < 4; ++j) {
      BF8 bh, bl;
      int rb = j*16 + l15;
      f32x4 v0 = *(const f32x4*)&Sl[rb][l4*8];
      f32x4 v1 = *(const f32x4*)&Sl[rb][l4*8+4];
      float ff[8] = {v0[0],v0[1],v0[2],v0[3],v1[0],v1[1],v1[2],v1[3]};
#pragma unroll
      for (int e = 0; e < 8; ++e) { bh.u[e] = topu(ff[e]); bl.u[e] = topu(ff[e]-hif(ff[e])); }
      acc[j] = MFMA(ah.b, bh.b, acc[j]);
      acc[j] = MFMA(ah.b, bl.b, acc[j]);
      acc[j] = MFMA(al.b, bh.b, acc[j]);
    }
  }
#pragma unroll
  for (int j = 0; j < 4; ++j)
#pragma unroll
    for (int r = 0; r < 4; ++r) {
      int grow = w*16 + l4*4 + r, gcol = j*16 + l15;
      float v = acc[j][r];
      Ghi[((size_t)s*RR + grow)*RR + gcol] = topu(v);
      Glo[((size_t)s*RR + grow)*RR + gcol] = topu(v - hif(v));
    }
}

// ---------------- fused: y = x*sub^T (MFMA), q = y^T G y, sparsemax, feature partials
__global__ __launch_bounds__(256) void fused_kernel(
    const float* __restrict__ x,
    const unsigned short* __restrict__ subhi, const unsigned short* __restrict__ sublo,
    const unsigned short* __restrict__ Ghi, const unsigned short* __restrict__ Glo,
    float inv_denom, int* __restrict__ amax, float* __restrict__ partial) {
  __shared__ __align__(16) float shmem[4*1088];  // 17408B: [0..8KB) = 2 stage bufs; epilogue y scratch
  __shared__ float ssqlds[MT];
  __shared__ float prq[MT][4];
  __shared__ float Wl[MT][4];

  int t = threadIdx.x;
  int lane = t & 63, w = t >> 6;
  int l15 = lane & 15, l4 = lane >> 4;
  int m0 = blockIdx.x * MT;

  f32x4 acc[2][4] = {};
  float ssqA = 0.f, ssqB = 0.f;

  auto stage = [&](int buf, int kc) {
    int row = t >> 3, gp = t & 7;
    int gl = gp ^ (row & 7);                   // swizzle involution (source side)
    const float* src = &x[(size_t)(m0 + row)*DD + kc*32 + gl*4];
    __builtin_amdgcn_global_load_lds((GVoid*)src,
        (LVoid*)((char*)shmem + buf*4096 + t*16), 16, 0, 0);
  };
  auto loadB = [&](BF8 (&bh)[4], BF8 (&bl)[4], int kc) {
#pragma unroll
    for (int nf = 0; nf < 4; ++nf) {
      size_t off = (size_t)(w*64 + nf*16 + l15)*DD + kc*32 + l4*8;
      bh[nf].u = *(const u16x8*)&subhi[off];
      bl[nf].u = *(const u16x8*)&sublo[off];
    }
  };
  auto kstep = [&](int buf, BF8 (&bh)[4], BF8 (&bl)[4]) {
    BF8 ah[2], al[2];
#pragma unroll
    for (int mf = 0; mf < 2; ++mf) {
      int row = mf*16 + l15;
      int g0 = (l4*2) ^ (row & 7), g1 = (l4*2 + 1) ^ (row & 7);
      f32x4 v0 = *(const f32x4*)((const char*)shmem + buf*4096 + (row*8 + g0)*16);
      f32x4 v1 = *(const f32x4*)((const char*)shmem + buf*4096 + (row*8 + g1)*16);
      float f0=v0[0], f1=v0[1], f2=v0[2], f3=v0[3];
      float g4=v1[0], g5=v1[1], g6=v1[2], g7=v1[3];
      float sq = f0*f0 + f1*f1 + f2*f2 + f3*f3 + g4*g4 + g5*g5 + g6*g6 + g7*g7;
      if (mf == 0) ssqA += sq; else ssqB += sq;
      ah[mf].w[0] = pack2(f0, f1); ah[mf].w[1] = pack2(f2, f3);
      ah[mf].w[2] = pack2(g4, g5); ah[mf].w[3] = pack2(g6, g7);
      al[mf].w[0] = pack2(f0-hif(f0), f1-hif(f1));
      al[mf].w[1] = pack2(f2-hif(f2), f3-hif(f3));
      al[mf].w[2] = pack2(g4-hif(g4), g5-hif(g5));
      al[mf].w[3] = pack2(g6-hif(g6), g7-hif(g7));
    }
#pragma unroll
    for (int nf = 0; nf < 4; ++nf)
#pragma unroll
      for (int mf = 0; mf < 2; ++mf) {
        acc[mf][nf] = MFMA(ah[mf].b, bh[nf].b, acc[mf][nf]);
        acc[mf][nf] = MFMA(ah[mf].b, bl[nf].b, acc[mf][nf]);
        acc[mf][nf] = MFMA(al[mf].b, bh[nf].b, acc[mf][nf]);
      }
  };

  BF8 bh0[4], bl0[4], bh1[4], bl1[4];
  stage(0, 0);
  loadB(bh0, bl0, 0);
  for (int kc = 0; kc < 16; kc += 2) {
    __syncthreads();
    stage(1, kc+1); loadB(bh1, bl1, kc+1);
    kstep(0, bh0, bl0);
    __syncthreads();
    if (kc < 14) { stage(0, kc+2); loadB(bh0, bl0, kc+2); }
    kstep(1, bh1, bl1);
  }

  // ssq reduce across l4 groups (all waves hold identical data; wave 0 writes)
  ssqA += __shfl_xor(ssqA, 16); ssqA += __shfl_xor(ssqA, 32);
  ssqB += __shfl_xor(ssqB, 16); ssqB += __shfl_xor(ssqB, 32);
  // G fragments (L2-resident); identity-order elements to match Ghi's scalar layout
  BF8 gh[2][4], gl2[2][4];
#pragma unroll
  for (int kf = 0; kf < 2; ++kf)
#pragma unroll
    for (int nf = 0; nf < 4; ++nf) {
      size_t off = (size_t)(w*RR + nf*16 + l15)*RR + kf*32 + l4*8;
      gh[kf][nf].u  = *(const u16x8*)&Ghi[off];
      gl2[kf][nf].u = *(const u16x8*)&Glo[off];
    }
  if (w == 0 && l4 == 0) { ssqlds[l15] = ssqA; ssqlds[16 + l15] = ssqB; }
  __syncthreads();   // all stage-buffer reads done; safe to reuse shmem as y scratch

  float* yw = shmem + w*1088;   // 16 rows x 68 per wave
#pragma unroll
  for (int h = 0; h < 2; ++h) {
#pragma unroll
    for (int nf = 0; nf < 4; ++nf)
#pragma unroll
      for (int r = 0; r < 4; ++r)
        yw[(l4*4 + r)*68 + nf*16 + l15] = acc[h][nf][r];
    BF8 yh[2], yl[2];
#pragma unroll
    for (int kf = 0; kf < 2; ++kf) {
      int base = l15*68 + kf*32 + l4*8;
      f32x4 v0 = *(const f32x4*)&yw[base];
      f32x4 v1 = *(const f32x4*)&yw[base+4];
      float ff[8] = {v0[0],v0[1],v0[2],v0[3],v1[0],v1[1],v1[2],v1[3]};
#pragma unroll
      for (int e = 0; e < 8; ++e) {
        yh[kf].u[e] = topu(ff[e]);
        yl[kf].u[e] = topu(ff[e] - hif(ff[e]));
      }
    }
    f32x4 z[4] = {};
#pragma unroll
    for (int nf = 0; nf < 4; ++nf)
#pragma unroll
      for (int kf = 0; kf < 2; ++kf) {
        z[nf] = MFMA(yh[kf].b, gh[kf][nf].b,  z[nf]);
        z[nf] = MFMA(yh[kf].b, gl2[kf][nf].b, z[nf]);
        z[nf] = MFMA(yl[kf].b, gh[kf][nf].b,  z[nf]);
      }
#pragma unroll
    for (int r = 0; r < 4; ++r) {
      float qp = z[0][r]*acc[h][0][r] + z[1][r]*acc[h][1][r]
               + z[2][r]*acc[h][2][r] + z[3][r]*acc[h][3][r];
      qp += __shfl_xor(qp, 1); qp += __shfl_xor(qp, 2);
      qp += __shfl_xor(qp, 4); qp += __shfl_xor(qp, 8);
      if (l15 == 0) prq[h*16 + l4*4 + r][w] = qp;
    }
  }
  __syncthreads();

  if (t < MT) {
    float ss = ssqlds[t];
    float inv = 1.f / fmaxf(sqrtf(ss), 1e-12f);
    float p0 = sqrtf(fmaxf(prq[t][0], 0.f)) * inv * inv_denom;
    float p1 = sqrtf(fmaxf(prq[t][1], 0.f)) * inv * inv_denom;
    float p2 = sqrtf(fmaxf(prq[t][2], 0.f)) * inv * inv_denom;
    float p3 = sqrtf(fmaxf(prq[t][3], 0.f)) * inv * inv_denom;
    float a0=p0, a1=p1, a2=p2, a3=p3, hi, lo;
    hi = fmaxf(a0,a1); lo = fminf(a0,a1); a0=hi; a1=lo;
    hi = fmaxf(a2,a3); lo = fminf(a2,a3); a2=hi; a3=lo;
    hi = fmaxf(a0,a2); lo = fminf(a0,a2); a0=hi; a2=lo;
    hi = fmaxf(a1,a3); lo = fminf(a1,a3); a1=hi; a3=lo;
    hi = fmaxf(a1,a2); lo = fminf(a1,a2); a1=hi; a2=lo;
    float c2 = a0+a1, c3 = c2+a2, c4s = c3+a3;
    int ksup = 1 + (2.f*a1 > c2-1.f) + (3.f*a2 > c3-1.f) + (4.f*a3 > c4s-1.f);
    float csel = (ksup==1) ? a0 : (ksup==2) ? c2 : (ksup==3) ? c3 : c4s;
    float tau = (csel - 1.f) / (float)ksup;
    float q0 = fmaxf(p0-tau, 0.f), q1 = fmaxf(p1-tau, 0.f);
    float q2 = fmaxf(p2-tau, 0.f), q3 = fmaxf(p3-tau, 0.f);
    int arg = 0; float best = q0;
    if (q1 > best) { best = q1; arg = 1; }
    if (q2 > best) { best = q2; arg = 2; }
    if (q3 > best) { best = q3; arg = 3; }
    amax[m0 + t] = arg;
    Wl[t][0] = q0*inv; Wl[t][1] = q1*inv; Wl[t][2] = q2*inv; Wl[t][3] = q3*inv;
  }
  __syncthreads();

  // per-subspace feature partials: grp handles 2 subspaces over all 32 tokens
  {
    int grp = t >> 7, dcol = t & 127;
    int s0 = grp*2;
    f32x4 a0 = {0,0,0,0}, a1 = {0,0,0,0};
#pragma unroll 8
    for (int tok = 0; tok < MT; ++tok) {
      f32x4 v = *(const f32x4*)&x[(size_t)(m0 + tok)*DD + dcol*4];
      float w0 = Wl[tok][s0], w1 = Wl[tok][s0+1];
      a0 += v * w0;
      a1 += v * w1;
    }
    *(f32x4*)&partial[((size_t)blockIdx.x*4 + s0  )*DD + dcol*4] = a0;
    *(f32x4*)&partial[((size_t)blockIdx.x*4 + s0+1)*DD + dcol*4] = a1;
  }
}

// ---------------- finish: majority vote + select/reduce partials -----------
__global__ __launch_bounds__(256) void finish_kernel(const int* __restrict__ amax,
    const float* __restrict__ partial, const int* __restrict__ mask,
    float* __restrict__ out) {
  __shared__ int cnt[4];
  __shared__ int vsh;
  int bb = blockIdx.x, t = threadIdx.x;
  if (t < 4) cnt[t] = 0;
  __syncthreads();
  int m = mask[bb];
  int c0=0, c1=0, c2=0, c3=0;
  for (int n = t; n < NN; n += 256) {
    if (n < m) {
      int a = amax[bb*NN + n];
      c0 += (a==0); c1 += (a==1); c2 += (a==2); c3 += (a==3);
    }
  }
  atomicAdd(&cnt[0], c0); atomicAdd(&cnt[1], c1);
  atomicAdd(&cnt[2], c2); atomicAdd(&cnt[3], c3);
  __syncthreads();
  if (t == 0) {
    int arg = 0, best = cnt[0];
    if (cnt[1] > best) { best = cnt[1]; arg = 1; }
    if (cnt[2] > best) { best = cnt[2]; arg = 2; }
    if (cnt[3] > best) { best = cnt[3]; arg = 3; }
    vsh = arg;
  }
  __syncthreads();
  int v = vsh;
  for (int d = t; d < DD; d += 256) {
    float f = 0.f;
#pragma unroll
    for (int c = 0; c < 32; ++c)
      f += partial[(((size_t)(bb*32 + c))*4 + v)*DD + d];
    out[bb*DD + d] = f;
  }
}

extern "C" void kernel_launch(void* const* d_in, const int* in_sizes, int n_in,
                              void* d_out, int out_size, void* d_ws, size_t ws_size,
                              hipStream_t stream) {
  const float* x    = (const float*)d_in[0];
  const int*   mask = (const int*)d_in[1];
  const float* sub  = (const float*)d_in[2];
  float* out = (float*)d_out;

  float* partial = (float*)d_ws;                         // 1024*4*512 f32 = 8 MB
  int*   amax    = (int*)(partial + (size_t)NBLK*4*DD);  // 32768 ints
  unsigned short* subhi = (unsigned short*)(amax + NT);  // 131072 u16
  unsigned short* sublo = subhi + OUTC*DD;
  unsigned short* Ghi   = sublo + OUTC*DD;               // 16384 u16
  unsigned short* Glo   = Ghi + SS*RR*RR;

  // SCALE = 1.718*exp(-count/30000) - 0.718, count = B = 32
  double scale = 1.718 * exp(-((double)BB) / 30000.0) - 0.718;
  float inv_denom = (float)(1.0 / ((double)DD * scale));

  prep_kernel<<<128 + SS, 256, 0, stream>>>(sub, subhi, sublo, Ghi, Glo);
  fused_kernel<<<NBLK, 256, 0, stream>>>(x, subhi, sublo, Ghi, Glo, inv_denom, amax, partial);
  finish_kernel<<<BB, 256, 0, stream>>>(amax, partial, mask, out);
}

// Round 4
// 98.349 us; speedup vs baseline: 1.1034x; 1.1034x over previous
//
#include <hip/hip_runtime.h>
#include <math.h>

#define BB 32
#define NN 1024
#define DD 512
#define SS 4
#define RR 64
#define OUTC 256          // SS*RR
#define NT (BB*NN)        // 32768 tokens
#define MT 64             // tokens per fused block
#define NBLK (NT/MT)      // 512
#define BPB (NN/MT)       // blocks per batch = 16

typedef float4 f4;
typedef float f32x4 __attribute__((ext_vector_type(4)));
typedef __bf16 bf16x8 __attribute__((ext_vector_type(8)));
typedef unsigned short u16x8 __attribute__((ext_vector_type(8)));

union BF8 { u16x8 u; bf16x8 b; unsigned w[4]; };

__device__ __forceinline__ float hif(float f) {
  return __uint_as_float(__float_as_uint(f) & 0xffff0000u);
}
__device__ __forceinline__ unsigned short topu(float f) {
  return (unsigned short)(__float_as_uint(f) >> 16);
}
// identity-order pack: (bf16(e0), bf16(e1)) -> u32 (e0 in low half)
__device__ __forceinline__ unsigned pack2(float e0, float e1) {
  return __builtin_amdgcn_perm(__float_as_uint(e1), __float_as_uint(e0), 0x07060302u);
}

#define MFMA(a,b,c) __builtin_amdgcn_mfma_f32_16x16x32_bf16((a),(b),(c),0,0,0)

// ---------------- prep: sub -> bf16 hi/lo; Gram G_s = S_s S_s^T -> bf16 hi/lo
__global__ __launch_bounds__(256) void prep_kernel(const float* __restrict__ sub,
    unsigned short* __restrict__ subhi, unsigned short* __restrict__ sublo,
    unsigned short* __restrict__ Ghi, unsigned short* __restrict__ Glo) {
  int t = threadIdx.x, blk = blockIdx.x;
  __shared__ __align__(16) float Sl[64][36];
  if (blk < 128) {
    int i = (blk*256 + t)*4;                   // 128*256*4 = OUTC*DD
    f4 v = *(const f4*)&sub[i];
    uint2 hh, ll;
    hh.x = pack2(v.x, v.y); hh.y = pack2(v.z, v.w);
    ll.x = pack2(v.x - hif(v.x), v.y - hif(v.y));
    ll.y = pack2(v.z - hif(v.z), v.w - hif(v.w));
    *(uint2*)&subhi[i] = hh;
    *(uint2*)&sublo[i] = ll;
    return;
  }
  int s = blk - 128;
  int lane = t & 63, w = t >> 6, l15 = lane & 15, l4 = lane >> 4;
  int row = t >> 2, seg = t & 3;               // staging: 64 rows x 4 segs of 8
  f4 r0, r1;
  f32x4 acc[4] = {{0,0,0,0},{0,0,0,0},{0,0,0,0},{0,0,0,0}};
  {
    const float* p = &sub[(size_t)(s*RR + row)*DD + seg*8];
    r0 = *(const f4*)p; r1 = *(const f4*)(p+4);
  }
  for (int kc = 0; kc < 16; ++kc) {
    __syncthreads();
    *(f4*)&Sl[row][seg*8]   = r0;
    *(f4*)&Sl[row][seg*8+4] = r1;
    __syncthreads();
    if (kc < 15) {
      const float* p = &sub[(size_t)(s*RR + row)*DD + (kc+1)*32 + seg*8];
      r0 = *(const f4*)p; r1 = *(const f4*)(p+4);
    }
    BF8 ah, al;
    {
      int ra = w*16 + l15;
      f32x4 v0 = *(const f32x4*)&Sl[ra][l4*8];
      f32x4 v1 = *(const f32x4*)&Sl[ra][l4*8+4];
      float ff[8] = {v0[0],v0[1],v0[2],v0[3],v1[0],v1[1],v1[2],v1[3]};
#pragma unroll
      for (int e = 0; e < 8; ++e) { ah.u[e] = topu(ff[e]); al.u[e] = topu(ff[e]-hif(ff[e])); }
    }
#pragma unroll
    for (int j = 0; j < 4; ++j) {
      BF8 bh, bl;
      int rb = j*16 + l15;
      f32x4 v0 = *(const f32x4*)&Sl[rb][l4*8];
      f32x4 v1 = *(const f32x4*)&Sl[rb][l4*8+4];
      float ff[8] = {v0[0],v0[1],v0[2],v0[3],v1[0],v1[1],v1[2],v1[3]};
#pragma unroll
      for (int e = 0; e < 8; ++e) { bh.u[e] = topu(ff[e]); bl.u[e] = topu(ff[e]-hif(ff[e])); }
      acc[j] = MFMA(ah.b, bh.b, acc[j]);
      acc[j] = MFMA(ah.b, bl.b, acc[j]);
      acc[j] = MFMA(al.b, bh.b, acc[j]);
    }
  }
#pragma unroll
  for (int j = 0; j < 4; ++j)
#pragma unroll
    for (int r = 0; r < 4; ++r) {
      int grow = w*16 + l4*4 + r, gcol = j*16 + l15;
      float v = acc[j][r];
      Ghi[((size_t)s*RR + grow)*RR + gcol] = topu(v);
      Glo[((size_t)s*RR + grow)*RR + gcol] = topu(v - hif(v));
    }
}

// ---------------- fused: y = x*sub^T (MFMA), q = y^T G y, sparsemax, partials
// 4 waves, wave w = subspace. MT=64 tokens. A staged as packed bf16 hi/lo in
// LDS (stride 40 u16 = 80B -> conflict-free 16-row fragment reads), converted
// ONCE per element at staging. x prefetched 2 chunks ahead in regs; B frags
// double-buffered 1 chunk ahead.
__global__ __launch_bounds__(256) void fused_kernel(
    const float* __restrict__ x,
    const unsigned short* __restrict__ subhi, const unsigned short* __restrict__ sublo,
    const unsigned short* __restrict__ Ghi, const unsigned short* __restrict__ Glo,
    float inv_denom, int* __restrict__ amax, float* __restrict__ partial) {
  __shared__ __align__(16) unsigned short ldsA[2][2][64*40];  // [buf][hi/lo], 20480 B
  __shared__ float ssqarr[64][4];
  __shared__ float prq[64][4];
  __shared__ float Wl[64][4];

  int t = threadIdx.x;
  int lane = t & 63, w = t >> 6;
  int l15 = lane & 15, l4 = lane >> 4;
  int m0 = blockIdx.x * MT;

  int srow = t >> 2, sseg = t & 3;
  const float* xrow = &x[(size_t)(m0 + srow)*DD + sseg*8];

  f32x4 acc[4][4] = {};
  float ssqp = 0.f;
  f4 r0, r1;

  auto gload = [&](int kc) {
    r0 = *(const f4*)(xrow + kc*32);
    r1 = *(const f4*)(xrow + kc*32 + 4);
  };
  auto cvtwrite = [&](int buf) {
    float f0=r0.x, f1=r0.y, f2=r0.z, f3=r0.w;
    float f4_=r1.x, f5=r1.y, f6=r1.z, f7=r1.w;
    ssqp += f0*f0+f1*f1+f2*f2+f3*f3+f4_*f4_+f5*f5+f6*f6+f7*f7;
    BF8 hi, lo;
    hi.w[0] = pack2(f0,f1); hi.w[1] = pack2(f2,f3);
    hi.w[2] = pack2(f4_,f5); hi.w[3] = pack2(f6,f7);
    lo.w[0] = pack2(f0-hif(f0), f1-hif(f1));
    lo.w[1] = pack2(f2-hif(f2), f3-hif(f3));
    lo.w[2] = pack2(f4_-hif(f4_), f5-hif(f5));
    lo.w[3] = pack2(f6-hif(f6), f7-hif(f7));
    *(u16x8*)&ldsA[buf][0][srow*40 + sseg*8] = hi.u;
    *(u16x8*)&ldsA[buf][1][srow*40 + sseg*8] = lo.u;
  };
  auto loadB = [&](BF8 (&bh)[4], BF8 (&bl)[4], int kc) {
#pragma unroll
    for (int nf = 0; nf < 4; ++nf) {
      size_t off = (size_t)(w*64 + nf*16 + l15)*DD + kc*32 + l4*8;
      bh[nf].u = *(const u16x8*)&subhi[off];
      bl[nf].u = *(const u16x8*)&sublo[off];
    }
  };
  auto kstep = [&](int buf, BF8 (&bh)[4], BF8 (&bl)[4]) {
#pragma unroll
    for (int mf = 0; mf < 4; ++mf) {
      BF8 ah, al;
      int row = mf*16 + l15;
      ah.u = *(const u16x8*)&ldsA[buf][0][row*40 + l4*8];
      al.u = *(const u16x8*)&ldsA[buf][1][row*40 + l4*8];
#pragma unroll
      for (int nf = 0; nf < 4; ++nf) {
        acc[mf][nf] = MFMA(ah.b, bh[nf].b, acc[mf][nf]);
        acc[mf][nf] = MFMA(ah.b, bl[nf].b, acc[mf][nf]);
        acc[mf][nf] = MFMA(al.b, bh[nf].b, acc[mf][nf]);
      }
    }
  };

  BF8 bh0[4], bl0[4], bh1[4], bl1[4];
  gload(0); cvtwrite(0); gload(1);
  loadB(bh0, bl0, 0);
  for (int kc = 0; kc < 16; kc += 2) {
    __syncthreads();                                    // buf0(kc) visible
    if (kc < 15) { loadB(bh1, bl1, kc+1); cvtwrite(1); if (kc < 14) gload(kc+2); }
    kstep(0, bh0, bl0);
    __syncthreads();                                    // buf1(kc+1) visible
    if (kc+1 < 15) { loadB(bh0, bl0, kc+2); cvtwrite(0); if (kc+1 < 14) gload(kc+3); }
    kstep(1, bh1, bl1);
  }

  ssqarr[srow][sseg] = ssqp;
  // G fragments (L2-resident); identity-order elements match Ghi scalar layout
  BF8 gh[2][4], gl2[2][4];
#pragma unroll
  for (int kf = 0; kf < 2; ++kf)
#pragma unroll
    for (int nf = 0; nf < 4; ++nf) {
      size_t off = (size_t)(w*RR + nf*16 + l15)*RR + kf*32 + l4*8;
      gh[kf][nf].u  = *(const u16x8*)&Ghi[off];
      gl2[kf][nf].u = *(const u16x8*)&Glo[off];
    }
  __syncthreads();   // all stage reads done; reuse ldsA as y scratch; ssqarr visible

  float* yw = (float*)&ldsA[0][0][0] + w*1088;   // 16 rows x 68 per wave
#pragma unroll
  for (int h = 0; h < 4; ++h) {
#pragma unroll
    for (int nf = 0; nf < 4; ++nf)
#pragma unroll
      for (int r = 0; r < 4; ++r)
        yw[(l4*4 + r)*68 + nf*16 + l15] = acc[h][nf][r];
    BF8 yh[2], yl[2];
#pragma unroll
    for (int kf = 0; kf < 2; ++kf) {
      int base = l15*68 + kf*32 + l4*8;
      f32x4 v0 = *(const f32x4*)&yw[base];
      f32x4 v1 = *(const f32x4*)&yw[base+4];
      float ff[8] = {v0[0],v0[1],v0[2],v0[3],v1[0],v1[1],v1[2],v1[3]};
#pragma unroll
      for (int e = 0; e < 8; ++e) {
        yh[kf].u[e] = topu(ff[e]);
        yl[kf].u[e] = topu(ff[e] - hif(ff[e]));
      }
    }
    f32x4 z[4] = {};
#pragma unroll
    for (int nf = 0; nf < 4; ++nf)
#pragma unroll
      for (int kf = 0; kf < 2; ++kf) {
        z[nf] = MFMA(yh[kf].b, gh[kf][nf].b,  z[nf]);
        z[nf] = MFMA(yh[kf].b, gl2[kf][nf].b, z[nf]);
        z[nf] = MFMA(yl[kf].b, gh[kf][nf].b,  z[nf]);
      }
#pragma unroll
    for (int r = 0; r < 4; ++r) {
      float qp = z[0][r]*acc[h][0][r] + z[1][r]*acc[h][1][r]
               + z[2][r]*acc[h][2][r] + z[3][r]*acc[h][3][r];
      qp += __shfl_xor(qp, 1); qp += __shfl_xor(qp, 2);
      qp += __shfl_xor(qp, 4); qp += __shfl_xor(qp, 8);
      if (l15 == 0) prq[h*16 + l4*4 + r][w] = qp;
    }
  }
  __syncthreads();

  if (t < MT) {
    float ss = ssqarr[t][0] + ssqarr[t][1] + ssqarr[t][2] + ssqarr[t][3];
    float inv = 1.f / fmaxf(sqrtf(ss), 1e-12f);
    float p0 = sqrtf(fmaxf(prq[t][0], 0.f)) * inv * inv_denom;
    float p1 = sqrtf(fmaxf(prq[t][1], 0.f)) * inv * inv_denom;
    float p2 = sqrtf(fmaxf(prq[t][2], 0.f)) * inv * inv_denom;
    float p3 = sqrtf(fmaxf(prq[t][3], 0.f)) * inv * inv_denom;
    float a0=p0, a1=p1, a2=p2, a3=p3, hi, lo;
    hi = fmaxf(a0,a1); lo = fminf(a0,a1); a0=hi; a1=lo;
    hi = fmaxf(a2,a3); lo = fminf(a2,a3); a2=hi; a3=lo;
    hi = fmaxf(a0,a2); lo = fminf(a0,a2); a0=hi; a2=lo;
    hi = fmaxf(a1,a3); lo = fminf(a1,a3); a1=hi; a3=lo;
    hi = fmaxf(a1,a2); lo = fminf(a1,a2); a1=hi; a2=lo;
    float c2 = a0+a1, c3 = c2+a2, c4s = c3+a3;
    int ksup = 1 + (2.f*a1 > c2-1.f) + (3.f*a2 > c3-1.f) + (4.f*a3 > c4s-1.f);
    float csel = (ksup==1) ? a0 : (ksup==2) ? c2 : (ksup==3) ? c3 : c4s;
    float tau = (csel - 1.f) / (float)ksup;
    float q0 = fmaxf(p0-tau, 0.f), q1 = fmaxf(p1-tau, 0.f);
    float q2 = fmaxf(p2-tau, 0.f), q3 = fmaxf(p3-tau, 0.f);
    int arg = 0; float best = q0;
    if (q1 > best) { best = q1; arg = 1; }
    if (q2 > best) { best = q2; arg = 2; }
    if (q3 > best) { best = q3; arg = 3; }
    amax[m0 + t] = arg;
    Wl[t][0] = q0*inv; Wl[t][1] = q1*inv; Wl[t][2] = q2*inv; Wl[t][3] = q3*inv;
  }
  __syncthreads();

  // per-subspace feature partials over this block's 64 tokens (x re-read = L2 hit)
  {
    int grp = t >> 7, dcol = t & 127;
    int s0 = grp*2;
    f32x4 a0 = {0,0,0,0}, a1 = {0,0,0,0};
#pragma unroll 8
    for (int tok = 0; tok < MT; ++tok) {
      f32x4 v = *(const f32x4*)&x[(size_t)(m0 + tok)*DD + dcol*4];
      float w0 = Wl[tok][s0], w1 = Wl[tok][s0+1];
      a0 += v * w0;
      a1 += v * w1;
    }
    *(f32x4*)&partial[((size_t)blockIdx.x*4 + s0  )*DD + dcol*4] = a0;
    *(f32x4*)&partial[((size_t)blockIdx.x*4 + s0+1)*DD + dcol*4] = a1;
  }
}

// ---------------- finish: majority vote + select/reduce partials -----------
__global__ __launch_bounds__(256) void finish_kernel(const int* __restrict__ amax,
    const float* __restrict__ partial, const int* __restrict__ mask,
    float* __restrict__ out) {
  __shared__ int cnt[4];
  __shared__ int vsh;
  int bb = blockIdx.x, t = threadIdx.x;
  if (t < 4) cnt[t] = 0;
  __syncthreads();
  int m = mask[bb];
  int c0=0, c1=0, c2=0, c3=0;
  for (int n = t; n < NN; n += 256) {
    if (n < m) {
      int a = amax[bb*NN + n];
      c0 += (a==0); c1 += (a==1); c2 += (a==2); c3 += (a==3);
    }
  }
  atomicAdd(&cnt[0], c0); atomicAdd(&cnt[1], c1);
  atomicAdd(&cnt[2], c2); atomicAdd(&cnt[3], c3);
  __syncthreads();
  if (t == 0) {
    int arg = 0, best = cnt[0];
    if (cnt[1] > best) { best = cnt[1]; arg = 1; }
    if (cnt[2] > best) { best = cnt[2]; arg = 2; }
    if (cnt[3] > best) { best = cnt[3]; arg = 3; }
    vsh = arg;
  }
  __syncthreads();
  int v = vsh;
  for (int d = t; d < DD; d += 256) {
    float f = 0.f;
#pragma unroll
    for (int c = 0; c < BPB; ++c)
      f += partial[(((size_t)(bb*BPB + c))*4 + v)*DD + d];
    out[bb*DD + d] = f;
  }
}

extern "C" void kernel_launch(void* const* d_in, const int* in_sizes, int n_in,
                              void* d_out, int out_size, void* d_ws, size_t ws_size,
                              hipStream_t stream) {
  const float* x    = (const float*)d_in[0];
  const int*   mask = (const int*)d_in[1];
  const float* sub  = (const float*)d_in[2];
  float* out = (float*)d_out;

  float* partial = (float*)d_ws;                         // 512*4*512 f32 = 4 MB
  int*   amax    = (int*)(partial + (size_t)NBLK*4*DD);  // 32768 ints
  unsigned short* subhi = (unsigned short*)(amax + NT);  // 131072 u16
  unsigned short* sublo = subhi + OUTC*DD;
  unsigned short* Ghi   = sublo + OUTC*DD;               // 16384 u16
  unsigned short* Glo   = Ghi + SS*RR*RR;

  // SCALE = 1.718*exp(-count/30000) - 0.718, count = B = 32
  double scale = 1.718 * exp(-((double)BB) / 30000.0) - 0.718;
  float inv_denom = (float)(1.0 / ((double)DD * scale));

  prep_kernel<<<128 + SS, 256, 0, stream>>>(sub, subhi, sublo, Ghi, Glo);
  fused_kernel<<<NBLK, 256, 0, stream>>>(x, subhi, sublo, Ghi, Glo, inv_denom, amax, partial);
  finish_kernel<<<BB, 256, 0, stream>>>(amax, partial, mask, out);
}

// Round 5
// 79.544 us; speedup vs baseline: 1.3642x; 1.2364x over previous
//
#include <hip/hip_runtime.h>
#include <math.h>

#define BB 32
#define NN 1024
#define DD 512
#define SS 4
#define RR 64
#define OUTC 256          // SS*RR
#define NT (BB*NN)        // 32768 tokens
#define MT 64             // tokens per fused block
#define NBLK (NT/MT)      // 512
#define BPB (NN/MT)       // blocks per batch = 16

typedef float4 f4;
typedef float f32x4 __attribute__((ext_vector_type(4)));
typedef __bf16 bf16x8 __attribute__((ext_vector_type(8)));
typedef unsigned short u16x8 __attribute__((ext_vector_type(8)));

union BF8 { u16x8 u; bf16x8 b; unsigned w[4]; };

__device__ __forceinline__ float hif(float f) {
  return __uint_as_float(__float_as_uint(f) & 0xffff0000u);
}
__device__ __forceinline__ unsigned short topu(float f) {
  return (unsigned short)(__float_as_uint(f) >> 16);
}
// identity-order pack: (bf16(e0), bf16(e1)) -> u32 (e0 in low half)
__device__ __forceinline__ unsigned pack2(float e0, float e1) {
  return __builtin_amdgcn_perm(__float_as_uint(e1), __float_as_uint(e0), 0x07060302u);
}

#define MFMA(a,b,c) __builtin_amdgcn_mfma_f32_16x16x32_bf16((a),(b),(c),0,0,0)

// ---------------- prep: sub -> bf16 hi/lo; Gram G_s = S_s S_s^T -> bf16 hi/lo
__global__ __launch_bounds__(256) void prep_kernel(const float* __restrict__ sub,
    unsigned short* __restrict__ subhi, unsigned short* __restrict__ sublo,
    unsigned short* __restrict__ Ghi, unsigned short* __restrict__ Glo) {
  int t = threadIdx.x, blk = blockIdx.x;
  __shared__ __align__(16) float Sl[64][36];
  if (blk < 128) {
    int i = (blk*256 + t)*4;                   // 128*256*4 = OUTC*DD
    f4 v = *(const f4*)&sub[i];
    uint2 hh, ll;
    hh.x = pack2(v.x, v.y); hh.y = pack2(v.z, v.w);
    ll.x = pack2(v.x - hif(v.x), v.y - hif(v.y));
    ll.y = pack2(v.z - hif(v.z), v.w - hif(v.w));
    *(uint2*)&subhi[i] = hh;
    *(uint2*)&sublo[i] = ll;
    return;
  }
  int s = blk - 128;
  int lane = t & 63, w = t >> 6, l15 = lane & 15, l4 = lane >> 4;
  int row = t >> 2, seg = t & 3;               // staging: 64 rows x 4 segs of 8
  f4 r0, r1;
  f32x4 acc[4] = {{0,0,0,0},{0,0,0,0},{0,0,0,0},{0,0,0,0}};
  {
    const float* p = &sub[(size_t)(s*RR + row)*DD + seg*8];
    r0 = *(const f4*)p; r1 = *(const f4*)(p+4);
  }
  for (int kc = 0; kc < 16; ++kc) {
    __syncthreads();
    *(f4*)&Sl[row][seg*8]   = r0;
    *(f4*)&Sl[row][seg*8+4] = r1;
    __syncthreads();
    if (kc < 15) {
      const float* p = &sub[(size_t)(s*RR + row)*DD + (kc+1)*32 + seg*8];
      r0 = *(const f4*)p; r1 = *(const f4*)(p+4);
    }
    BF8 ah, al;
    {
      int ra = w*16 + l15;
      f32x4 v0 = *(const f32x4*)&Sl[ra][l4*8];
      f32x4 v1 = *(const f32x4*)&Sl[ra][l4*8+4];
      float ff[8] = {v0[0],v0[1],v0[2],v0[3],v1[0],v1[1],v1[2],v1[3]};
#pragma unroll
      for (int e = 0; e < 8; ++e) { ah.u[e] = topu(ff[e]); al.u[e] = topu(ff[e]-hif(ff[e])); }
    }
#pragma unroll
    for (int j = 0; j < 4; ++j) {
      BF8 bh, bl;
      int rb = j*16 + l15;
      f32x4 v0 = *(const f32x4*)&Sl[rb][l4*8];
      f32x4 v1 = *(const f32x4*)&Sl[rb][l4*8+4];
      float ff[8] = {v0[0],v0[1],v0[2],v0[3],v1[0],v1[1],v1[2],v1[3]};
#pragma unroll
      for (int e = 0; e < 8; ++e) { bh.u[e] = topu(ff[e]); bl.u[e] = topu(ff[e]-hif(ff[e])); }
      acc[j] = MFMA(ah.b, bh.b, acc[j]);
      acc[j] = MFMA(ah.b, bl.b, acc[j]);
      acc[j] = MFMA(al.b, bh.b, acc[j]);
    }
  }
#pragma unroll
  for (int j = 0; j < 4; ++j)
#pragma unroll
    for (int r = 0; r < 4; ++r) {
      int grow = w*16 + l4*4 + r, gcol = j*16 + l15;
      float v = acc[j][r];
      Ghi[((size_t)s*RR + grow)*RR + gcol] = topu(v);
      Glo[((size_t)s*RR + grow)*RR + gcol] = topu(v - hif(v));
    }
}

// ---------------- fused: y = x*sub^T (MFMA), q = y^T G y, sparsemax, partials
// 8 waves (512 thr): wave w -> subspace s=w&3, col-half ch=w>>2.
// Each wave: 64 tokens x 32 cols. acc[4][2] f32x4 = 32 VGPR; B dbuf = 32 VGPR.
// A staged once as packed bf16 hi/lo in LDS (stride 40 u16).
__global__ __launch_bounds__(512, 4) void fused_kernel(
    const float* __restrict__ x,
    const unsigned short* __restrict__ subhi, const unsigned short* __restrict__ sublo,
    const unsigned short* __restrict__ Ghi, const unsigned short* __restrict__ Glo,
    float inv_denom, int* __restrict__ amax, float* __restrict__ partial) {
  __shared__ __align__(16) unsigned short ldsA[2][2][64*40];  // 20480 B, reused as y scratch
  __shared__ float ssqarr[64][8];
  __shared__ float prq2[64][4][2];
  __shared__ float Wl[64][4];

  int t = threadIdx.x;
  int lane = t & 63, w = t >> 6;
  int s = w & 3, ch = w >> 2;
  int l15 = lane & 15, l4 = lane >> 4;
  int m0 = blockIdx.x * MT;

  int srow = t >> 3, sseg = t & 7;             // staging: 64 rows x 8 segs of 4 floats
  const float* xrow = &x[(size_t)(m0 + srow)*DD + sseg*4];

  f32x4 acc[4][2] = {};
  float ssqp = 0.f;

  auto gload = [&](int kc) -> f4 {
    return *(const f4*)(xrow + kc*32);
  };
  auto cvtwrite = [&](int buf, f4 v) {
    float f0=v.x, f1=v.y, f2=v.z, f3=v.w;
    ssqp += f0*f0 + f1*f1 + f2*f2 + f3*f3;
    uint2 hh, ll;
    hh.x = pack2(f0,f1); hh.y = pack2(f2,f3);
    ll.x = pack2(f0-hif(f0), f1-hif(f1));
    ll.y = pack2(f2-hif(f2), f3-hif(f3));
    *(uint2*)&ldsA[buf][0][srow*40 + sseg*4] = hh;
    *(uint2*)&ldsA[buf][1][srow*40 + sseg*4] = ll;
  };
  auto loadB = [&](BF8 (&bh)[2], BF8 (&bl)[2], int kc) {
#pragma unroll
    for (int nf = 0; nf < 2; ++nf) {
      size_t off = (size_t)(s*64 + ch*32 + nf*16 + l15)*DD + kc*32 + l4*8;
      bh[nf].u = *(const u16x8*)&subhi[off];
      bl[nf].u = *(const u16x8*)&sublo[off];
    }
  };
  auto kstep = [&](int buf, BF8 (&bh)[2], BF8 (&bl)[2]) {
#pragma unroll
    for (int mf = 0; mf < 4; ++mf) {
      BF8 ah, al;
      int row = mf*16 + l15;
      ah.u = *(const u16x8*)&ldsA[buf][0][row*40 + l4*8];
      al.u = *(const u16x8*)&ldsA[buf][1][row*40 + l4*8];
#pragma unroll
      for (int nf = 0; nf < 2; ++nf) {
        acc[mf][nf] = MFMA(ah.b, bh[nf].b, acc[mf][nf]);
        acc[mf][nf] = MFMA(ah.b, bl[nf].b, acc[mf][nf]);
        acc[mf][nf] = MFMA(al.b, bh[nf].b, acc[mf][nf]);
      }
    }
  };

  BF8 bh0[2], bl0[2], bh1[2], bl1[2];
  {
    f4 r = gload(0);
    cvtwrite(0, r);
  }
  f4 rA = gload(1);
  f4 rB = gload(2);
  loadB(bh0, bl0, 0);
  for (int kc = 0; kc < 16; kc += 2) {
    __syncthreads();                       // buf0(kc) written; buf1(kc-1) reads done
    loadB(bh1, bl1, kc+1);
    cvtwrite(1, rA);                       // chunk kc+1
    if (kc < 14) rA = gload(kc+3);
    kstep(0, bh0, bl0);                    // chunk kc
    __syncthreads();                       // buf1(kc+1) written; buf0(kc) reads done
    if (kc < 14) {
      loadB(bh0, bl0, kc+2);
      cvtwrite(0, rB);                     // chunk kc+2
      if (kc < 12) rB = gload(kc+4);
    }
    kstep(1, bh1, bl1);                    // chunk kc+1
  }
  ssqarr[srow][sseg] = ssqp;

  // ---- epilogue: q = y^T G y, both col-halves cooperating per subspace ----
  BF8 gh[2][2], gl2[2][2];                 // [kf][nf_local]
#pragma unroll
  for (int kf = 0; kf < 2; ++kf)
#pragma unroll
    for (int nf = 0; nf < 2; ++nf) {
      size_t off = (size_t)(s*RR + (ch*2 + nf)*16 + l15)*RR + kf*32 + l4*8;
      gh[kf][nf].u  = *(const u16x8*)&Ghi[off];
      gl2[kf][nf].u = *(const u16x8*)&Glo[off];
    }
  float* ysc = (float*)&ldsA[0][0][0];     // [s][16][68] f32 = 17408 B

#pragma unroll
  for (int h = 0; h < 4; ++h) {
    __syncthreads();                       // prior ysc readers / main-loop reads done
#pragma unroll
    for (int nf = 0; nf < 2; ++nf)
#pragma unroll
      for (int r = 0; r < 4; ++r)
        ysc[s*1088 + (l4*4 + r)*68 + ch*32 + nf*16 + l15] = acc[h][nf][r];
    __syncthreads();                       // ysc[s] complete (both halves)
    BF8 yh[2], yl[2];
#pragma unroll
    for (int kf = 0; kf < 2; ++kf) {
      int base = s*1088 + l15*68 + kf*32 + l4*8;
      f32x4 v0 = *(const f32x4*)&ysc[base];
      f32x4 v1 = *(const f32x4*)&ysc[base+4];
      float ff[8] = {v0[0],v0[1],v0[2],v0[3],v1[0],v1[1],v1[2],v1[3]};
#pragma unroll
      for (int e = 0; e < 8; ++e) {
        yh[kf].u[e] = topu(ff[e]);
        yl[kf].u[e] = topu(ff[e] - hif(ff[e]));
      }
    }
    f32x4 z[2] = {};
#pragma unroll
    for (int nf = 0; nf < 2; ++nf)
#pragma unroll
      for (int kf = 0; kf < 2; ++kf) {
        z[nf] = MFMA(yh[kf].b, gh[kf][nf].b,  z[nf]);
        z[nf] = MFMA(yh[kf].b, gl2[kf][nf].b, z[nf]);
        z[nf] = MFMA(yl[kf].b, gh[kf][nf].b,  z[nf]);
      }
#pragma unroll
    for (int r = 0; r < 4; ++r) {
      float qp = z[0][r]*acc[h][0][r] + z[1][r]*acc[h][1][r];
      qp += __shfl_xor(qp, 1); qp += __shfl_xor(qp, 2);
      qp += __shfl_xor(qp, 4); qp += __shfl_xor(qp, 8);
      if (l15 == 0) prq2[h*16 + l4*4 + r][s][ch] = qp;
    }
  }
  __syncthreads();

  if (t < MT) {
    float ss = 0.f;
#pragma unroll
    for (int g = 0; g < 8; ++g) ss += ssqarr[t][g];
    float inv = 1.f / fmaxf(sqrtf(ss), 1e-12f);
    float p0 = sqrtf(fmaxf(prq2[t][0][0] + prq2[t][0][1], 0.f)) * inv * inv_denom;
    float p1 = sqrtf(fmaxf(prq2[t][1][0] + prq2[t][1][1], 0.f)) * inv * inv_denom;
    float p2 = sqrtf(fmaxf(prq2[t][2][0] + prq2[t][2][1], 0.f)) * inv * inv_denom;
    float p3 = sqrtf(fmaxf(prq2[t][3][0] + prq2[t][3][1], 0.f)) * inv * inv_denom;
    float a0=p0, a1=p1, a2=p2, a3=p3, hi, lo;
    hi = fmaxf(a0,a1); lo = fminf(a0,a1); a0=hi; a1=lo;
    hi = fmaxf(a2,a3); lo = fminf(a2,a3); a2=hi; a3=lo;
    hi = fmaxf(a0,a2); lo = fminf(a0,a2); a0=hi; a2=lo;
    hi = fmaxf(a1,a3); lo = fminf(a1,a3); a1=hi; a3=lo;
    hi = fmaxf(a1,a2); lo = fminf(a1,a2); a1=hi; a2=lo;
    float c2 = a0+a1, c3 = c2+a2, c4s = c3+a3;
    int ksup = 1 + (2.f*a1 > c2-1.f) + (3.f*a2 > c3-1.f) + (4.f*a3 > c4s-1.f);
    float csel = (ksup==1) ? a0 : (ksup==2) ? c2 : (ksup==3) ? c3 : c4s;
    float tau = (csel - 1.f) / (float)ksup;
    float q0 = fmaxf(p0-tau, 0.f), q1 = fmaxf(p1-tau, 0.f);
    float q2 = fmaxf(p2-tau, 0.f), q3 = fmaxf(p3-tau, 0.f);
    int arg = 0; float best = q0;
    if (q1 > best) { best = q1; arg = 1; }
    if (q2 > best) { best = q2; arg = 2; }
    if (q3 > best) { best = q3; arg = 3; }
    amax[m0 + t] = arg;
    Wl[t][0] = q0*inv; Wl[t][1] = q1*inv; Wl[t][2] = q2*inv; Wl[t][3] = q3*inv;
  }
  __syncthreads();

  // per-subspace feature partials over this block's 64 tokens (x re-read ~L2)
  {
    int grp = t >> 7, dcol = t & 127;      // grp = subspace, 128 dcols of f32x4
    f32x4 a0 = {0,0,0,0};
#pragma unroll 8
    for (int tok = 0; tok < MT; ++tok) {
      f32x4 v = *(const f32x4*)&x[(size_t)(m0 + tok)*DD + dcol*4];
      a0 += v * Wl[tok][grp];
    }
    *(f32x4*)&partial[((size_t)blockIdx.x*4 + grp)*DD + dcol*4] = a0;
  }
}

// ---------------- finish: majority vote + select/reduce partials -----------
__global__ __launch_bounds__(256) void finish_kernel(const int* __restrict__ amax,
    const float* __restrict__ partial, const int* __restrict__ mask,
    float* __restrict__ out) {
  __shared__ int cnt[4];
  __shared__ int vsh;
  int bb = blockIdx.x, t = threadIdx.x;
  if (t < 4) cnt[t] = 0;
  __syncthreads();
  int m = mask[bb];
  int c0=0, c1=0, c2=0, c3=0;
  for (int n = t; n < NN; n += 256) {
    if (n < m) {
      int a = amax[bb*NN + n];
      c0 += (a==0); c1 += (a==1); c2 += (a==2); c3 += (a==3);
    }
  }
  atomicAdd(&cnt[0], c0); atomicAdd(&cnt[1], c1);
  atomicAdd(&cnt[2], c2); atomicAdd(&cnt[3], c3);
  __syncthreads();
  if (t == 0) {
    int arg = 0, best = cnt[0];
    if (cnt[1] > best) { best = cnt[1]; arg = 1; }
    if (cnt[2] > best) { best = cnt[2]; arg = 2; }
    if (cnt[3] > best) { best = cnt[3]; arg = 3; }
    vsh = arg;
  }
  __syncthreads();
  int v = vsh;
  for (int d = t; d < DD; d += 256) {
    float f = 0.f;
#pragma unroll
    for (int c = 0; c < BPB; ++c)
      f += partial[(((size_t)(bb*BPB + c))*4 + v)*DD + d];
    out[bb*DD + d] = f;
  }
}

extern "C" void kernel_launch(void* const* d_in, const int* in_sizes, int n_in,
                              void* d_out, int out_size, void* d_ws, size_t ws_size,
                              hipStream_t stream) {
  const float* x    = (const float*)d_in[0];
  const int*   mask = (const int*)d_in[1];
  const float* sub  = (const float*)d_in[2];
  float* out = (float*)d_out;

  float* partial = (float*)d_ws;                         // 512*4*512 f32 = 4 MB
  int*   amax    = (int*)(partial + (size_t)NBLK*4*DD);  // 32768 ints
  unsigned short* subhi = (unsigned short*)(amax + NT);  // 131072 u16
  unsigned short* sublo = subhi + OUTC*DD;
  unsigned short* Ghi   = sublo + OUTC*DD;               // 16384 u16
  unsigned short* Glo   = Ghi + SS*RR*RR;

  // SCALE = 1.718*exp(-count/30000) - 0.718, count = B = 32
  double scale = 1.718 * exp(-((double)BB) / 30000.0) - 0.718;
  float inv_denom = (float)(1.0 / ((double)DD * scale));

  prep_kernel<<<128 + SS, 256, 0, stream>>>(sub, subhi, sublo, Ghi, Glo);
  fused_kernel<<<NBLK, 512, 0, stream>>>(x, subhi, sublo, Ghi, Glo, inv_denom, amax, partial);
  finish_kernel<<<BB, 256, 0, stream>>>(amax, partial, mask, out);
}

// Round 6
// 79.464 us; speedup vs baseline: 1.3656x; 1.0010x over previous
//
#include <hip/hip_runtime.h>
#include <math.h>

#define BB 32
#define NN 1024
#define DD 512
#define SS 4
#define RR 64
#define OUTC 256          // SS*RR
#define NT (BB*NN)        // 32768 tokens
#define MT 64             // tokens per fused block
#define NBLK (NT/MT)      // 512
#define BPB (NN/MT)       // blocks per batch = 16

typedef float4 f4;
typedef float f32x4 __attribute__((ext_vector_type(4)));
typedef __bf16 bf16x8 __attribute__((ext_vector_type(8)));
typedef unsigned short u16x8 __attribute__((ext_vector_type(8)));

union BF8 { u16x8 u; bf16x8 b; unsigned w[4]; };

__device__ __forceinline__ float hif(float f) {
  return __uint_as_float(__float_as_uint(f) & 0xffff0000u);
}
__device__ __forceinline__ unsigned short topu(float f) {
  return (unsigned short)(__float_as_uint(f) >> 16);
}
// identity-order pack: (bf16(e0), bf16(e1)) -> u32 (e0 in low half)
__device__ __forceinline__ unsigned pack2(float e0, float e1) {
  return __builtin_amdgcn_perm(__float_as_uint(e1), __float_as_uint(e0), 0x07060302u);
}

#define MFMA(a,b,c) __builtin_amdgcn_mfma_f32_16x16x32_bf16((a),(b),(c),0,0,0)

// Barrier that does NOT drain vmcnt: LDS ops must complete (lgkmcnt(0)) for
// cross-wave visibility, but in-flight register-dest global loads (x/B
// prefetch) survive across it. __syncthreads() would emit a full
// s_waitcnt vmcnt(0) drain (seq-cst workgroup fence) and kill the pipeline.
#define BARRIER_LGKM() do { \
  asm volatile("s_waitcnt lgkmcnt(0)" ::: "memory"); \
  __builtin_amdgcn_s_barrier(); \
} while (0)

// ---------------- prep: sub -> bf16 hi/lo; Gram G_s = S_s S_s^T -> bf16 hi/lo
__global__ __launch_bounds__(256) void prep_kernel(const float* __restrict__ sub,
    unsigned short* __restrict__ subhi, unsigned short* __restrict__ sublo,
    unsigned short* __restrict__ Ghi, unsigned short* __restrict__ Glo) {
  int t = threadIdx.x, blk = blockIdx.x;
  __shared__ __align__(16) float Sl[64][36];
  if (blk < 128) {
    int i = (blk*256 + t)*4;                   // 128*256*4 = OUTC*DD
    f4 v = *(const f4*)&sub[i];
    uint2 hh, ll;
    hh.x = pack2(v.x, v.y); hh.y = pack2(v.z, v.w);
    ll.x = pack2(v.x - hif(v.x), v.y - hif(v.y));
    ll.y = pack2(v.z - hif(v.z), v.w - hif(v.w));
    *(uint2*)&subhi[i] = hh;
    *(uint2*)&sublo[i] = ll;
    return;
  }
  int s = blk - 128;
  int lane = t & 63, w = t >> 6, l15 = lane & 15, l4 = lane >> 4;
  int row = t >> 2, seg = t & 3;               // staging: 64 rows x 4 segs of 8
  f4 r0, r1;
  f32x4 acc[4] = {{0,0,0,0},{0,0,0,0},{0,0,0,0},{0,0,0,0}};
  {
    const float* p = &sub[(size_t)(s*RR + row)*DD + seg*8];
    r0 = *(const f4*)p; r1 = *(const f4*)(p+4);
  }
  for (int kc = 0; kc < 16; ++kc) {
    __syncthreads();
    *(f4*)&Sl[row][seg*8]   = r0;
    *(f4*)&Sl[row][seg*8+4] = r1;
    __syncthreads();
    if (kc < 15) {
      const float* p = &sub[(size_t)(s*RR + row)*DD + (kc+1)*32 + seg*8];
      r0 = *(const f4*)p; r1 = *(const f4*)(p+4);
    }
    BF8 ah, al;
    {
      int ra = w*16 + l15;
      f32x4 v0 = *(const f32x4*)&Sl[ra][l4*8];
      f32x4 v1 = *(const f32x4*)&Sl[ra][l4*8+4];
      float ff[8] = {v0[0],v0[1],v0[2],v0[3],v1[0],v1[1],v1[2],v1[3]};
#pragma unroll
      for (int e = 0; e < 8; ++e) { ah.u[e] = topu(ff[e]); al.u[e] = topu(ff[e]-hif(ff[e])); }
    }
#pragma unroll
    for (int j = 0; j < 4; ++j) {
      BF8 bh, bl;
      int rb = j*16 + l15;
      f32x4 v0 = *(const f32x4*)&Sl[rb][l4*8];
      f32x4 v1 = *(const f32x4*)&Sl[rb][l4*8+4];
      float ff[8] = {v0[0],v0[1],v0[2],v0[3],v1[0],v1[1],v1[2],v1[3]};
#pragma unroll
      for (int e = 0; e < 8; ++e) { bh.u[e] = topu(ff[e]); bl.u[e] = topu(ff[e]-hif(ff[e])); }
      acc[j] = MFMA(ah.b, bh.b, acc[j]);
      acc[j] = MFMA(ah.b, bl.b, acc[j]);
      acc[j] = MFMA(al.b, bh.b, acc[j]);
    }
  }
#pragma unroll
  for (int j = 0; j < 4; ++j)
#pragma unroll
    for (int r = 0; r < 4; ++r) {
      int grow = w*16 + l4*4 + r, gcol = j*16 + l15;
      float v = acc[j][r];
      Ghi[((size_t)s*RR + grow)*RR + gcol] = topu(v);
      Glo[((size_t)s*RR + grow)*RR + gcol] = topu(v - hif(v));
    }
}

// ---------------- fused: y = x*sub^T (MFMA), q = y^T G y, sparsemax, partials
// 8 waves (512 thr): wave w -> subspace s=w&3, col-half ch=w>>2.
__global__ __launch_bounds__(512, 4) void fused_kernel(
    const float* __restrict__ x,
    const unsigned short* __restrict__ subhi, const unsigned short* __restrict__ sublo,
    const unsigned short* __restrict__ Ghi, const unsigned short* __restrict__ Glo,
    float inv_denom, int* __restrict__ amax, float* __restrict__ partial) {
  __shared__ __align__(16) unsigned short ldsA[2][2][64*40];  // 20480 B, reused as y scratch
  __shared__ float ssqarr[64][8];
  __shared__ float prq2[64][4][2];
  __shared__ float Wl[64][4];

  int t = threadIdx.x;
  int lane = t & 63, w = t >> 6;
  int s = w & 3, ch = w >> 2;
  int l15 = lane & 15, l4 = lane >> 4;
  int m0 = blockIdx.x * MT;

  int srow = t >> 3, sseg = t & 7;             // staging: 64 rows x 8 segs of 4 floats
  const float* xrow = &x[(size_t)(m0 + srow)*DD + sseg*4];

  f32x4 acc[4][2] = {};
  float ssqp = 0.f;

  auto gload = [&](int kc) -> f4 {
    return *(const f4*)(xrow + kc*32);
  };
  auto cvtwrite = [&](int buf, f4 v) {
    float f0=v.x, f1=v.y, f2=v.z, f3=v.w;
    ssqp += f0*f0 + f1*f1 + f2*f2 + f3*f3;
    uint2 hh, ll;
    hh.x = pack2(f0,f1); hh.y = pack2(f2,f3);
    ll.x = pack2(f0-hif(f0), f1-hif(f1));
    ll.y = pack2(f2-hif(f2), f3-hif(f3));
    *(uint2*)&ldsA[buf][0][srow*40 + sseg*4] = hh;
    *(uint2*)&ldsA[buf][1][srow*40 + sseg*4] = ll;
  };
  auto loadB = [&](BF8 (&bh)[2], BF8 (&bl)[2], int kc) {
#pragma unroll
    for (int nf = 0; nf < 2; ++nf) {
      size_t off = (size_t)(s*64 + ch*32 + nf*16 + l15)*DD + kc*32 + l4*8;
      bh[nf].u = *(const u16x8*)&subhi[off];
      bl[nf].u = *(const u16x8*)&sublo[off];
    }
  };
  auto kstep = [&](int buf, BF8 (&bh)[2], BF8 (&bl)[2]) {
#pragma unroll
    for (int mf = 0; mf < 4; ++mf) {
      BF8 ah, al;
      int row = mf*16 + l15;
      ah.u = *(const u16x8*)&ldsA[buf][0][row*40 + l4*8];
      al.u = *(const u16x8*)&ldsA[buf][1][row*40 + l4*8];
#pragma unroll
      for (int nf = 0; nf < 2; ++nf) {
        acc[mf][nf] = MFMA(ah.b, bh[nf].b, acc[mf][nf]);
        acc[mf][nf] = MFMA(ah.b, bl[nf].b, acc[mf][nf]);
        acc[mf][nf] = MFMA(al.b, bh[nf].b, acc[mf][nf]);
      }
    }
  };

  BF8 bh0[2], bl0[2], bh1[2], bl1[2];
  {
    f4 r = gload(0);
    cvtwrite(0, r);
  }
  f4 rA = gload(1);
  f4 rB = gload(2);
  loadB(bh0, bl0, 0);
  for (int kc = 0; kc < 16; kc += 2) {
    BARRIER_LGKM();                        // buf0(kc) visible; buf1(kc-1) reads done
    loadB(bh1, bl1, kc+1);
    cvtwrite(1, rA);                       // chunk kc+1
    if (kc < 14) rA = gload(kc+3);
    kstep(0, bh0, bl0);                    // chunk kc
    BARRIER_LGKM();                        // buf1(kc+1) visible; buf0(kc) reads done
    if (kc < 14) {
      loadB(bh0, bl0, kc+2);
      cvtwrite(0, rB);                     // chunk kc+2
      if (kc < 12) rB = gload(kc+4);
    }
    kstep(1, bh1, bl1);                    // chunk kc+1
  }
  ssqarr[srow][sseg] = ssqp;

  // ---- epilogue: q = y^T G y, both col-halves cooperating per subspace ----
  BF8 gh[2][2], gl2[2][2];                 // [kf][nf_local]
#pragma unroll
  for (int kf = 0; kf < 2; ++kf)
#pragma unroll
    for (int nf = 0; nf < 2; ++nf) {
      size_t off = (size_t)(s*RR + (ch*2 + nf)*16 + l15)*RR + kf*32 + l4*8;
      gh[kf][nf].u  = *(const u16x8*)&Ghi[off];
      gl2[kf][nf].u = *(const u16x8*)&Glo[off];
    }
  float* ysc = (float*)&ldsA[0][0][0];     // [s][16][68] f32 = 17408 B

#pragma unroll
  for (int h = 0; h < 4; ++h) {
    __syncthreads();                       // prior ysc readers / main-loop reads done
#pragma unroll
    for (int nf = 0; nf < 2; ++nf)
#pragma unroll
      for (int r = 0; r < 4; ++r)
        ysc[s*1088 + (l4*4 + r)*68 + ch*32 + nf*16 + l15] = acc[h][nf][r];
    __syncthreads();                       // ysc[s] complete (both halves)
    BF8 yh[2], yl[2];
#pragma unroll
    for (int kf = 0; kf < 2; ++kf) {
      int base = s*1088 + l15*68 + kf*32 + l4*8;
      f32x4 v0 = *(const f32x4*)&ysc[base];
      f32x4 v1 = *(const f32x4*)&ysc[base+4];
      float ff[8] = {v0[0],v0[1],v0[2],v0[3],v1[0],v1[1],v1[2],v1[3]};
#pragma unroll
      for (int e = 0; e < 8; ++e) {
        yh[kf].u[e] = topu(ff[e]);
        yl[kf].u[e] = topu(ff[e] - hif(ff[e]));
      }
    }
    f32x4 z[2] = {};
#pragma unroll
    for (int nf = 0; nf < 2; ++nf)
#pragma unroll
      for (int kf = 0; kf < 2; ++kf) {
        z[nf] = MFMA(yh[kf].b, gh[kf][nf].b,  z[nf]);
        z[nf] = MFMA(yh[kf].b, gl2[kf][nf].b, z[nf]);
        z[nf] = MFMA(yl[kf].b, gh[kf][nf].b,  z[nf]);
      }
#pragma unroll
    for (int r = 0; r < 4; ++r) {
      float qp = z[0][r]*acc[h][0][r] + z[1][r]*acc[h][1][r];
      qp += __shfl_xor(qp, 1); qp += __shfl_xor(qp, 2);
      qp += __shfl_xor(qp, 4); qp += __shfl_xor(qp, 8);
      if (l15 == 0) prq2[h*16 + l4*4 + r][s][ch] = qp;
    }
  }
  __syncthreads();

  if (t < MT) {
    float ss = 0.f;
#pragma unroll
    for (int g = 0; g < 8; ++g) ss += ssqarr[t][g];
    float inv = 1.f / fmaxf(sqrtf(ss), 1e-12f);
    float p0 = sqrtf(fmaxf(prq2[t][0][0] + prq2[t][0][1], 0.f)) * inv * inv_denom;
    float p1 = sqrtf(fmaxf(prq2[t][1][0] + prq2[t][1][1], 0.f)) * inv * inv_denom;
    float p2 = sqrtf(fmaxf(prq2[t][2][0] + prq2[t][2][1], 0.f)) * inv * inv_denom;
    float p3 = sqrtf(fmaxf(prq2[t][3][0] + prq2[t][3][1], 0.f)) * inv * inv_denom;
    float a0=p0, a1=p1, a2=p2, a3=p3, hi, lo;
    hi = fmaxf(a0,a1); lo = fminf(a0,a1); a0=hi; a1=lo;
    hi = fmaxf(a2,a3); lo = fminf(a2,a3); a2=hi; a3=lo;
    hi = fmaxf(a0,a2); lo = fminf(a0,a2); a0=hi; a2=lo;
    hi = fmaxf(a1,a3); lo = fminf(a1,a3); a1=hi; a3=lo;
    hi = fmaxf(a1,a2); lo = fminf(a1,a2); a1=hi; a2=lo;
    float c2 = a0+a1, c3 = c2+a2, c4s = c3+a3;
    int ksup = 1 + (2.f*a1 > c2-1.f) + (3.f*a2 > c3-1.f) + (4.f*a3 > c4s-1.f);
    float csel = (ksup==1) ? a0 : (ksup==2) ? c2 : (ksup==3) ? c3 : c4s;
    float tau = (csel - 1.f) / (float)ksup;
    float q0 = fmaxf(p0-tau, 0.f), q1 = fmaxf(p1-tau, 0.f);
    float q2 = fmaxf(p2-tau, 0.f), q3 = fmaxf(p3-tau, 0.f);
    int arg = 0; float best = q0;
    if (q1 > best) { best = q1; arg = 1; }
    if (q2 > best) { best = q2; arg = 2; }
    if (q3 > best) { best = q3; arg = 3; }
    amax[m0 + t] = arg;
    Wl[t][0] = q0*inv; Wl[t][1] = q1*inv; Wl[t][2] = q2*inv; Wl[t][3] = q3*inv;
  }
  __syncthreads();

  // per-subspace feature partials over this block's 64 tokens (x re-read ~L2/L3)
  {
    int grp = t >> 7, dcol = t & 127;      // grp = subspace, 128 dcols of f32x4
    f32x4 a0 = {0,0,0,0};
#pragma unroll 8
    for (int tok = 0; tok < MT; ++tok) {
      f32x4 v = *(const f32x4*)&x[(size_t)(m0 + tok)*DD + dcol*4];
      a0 += v * Wl[tok][grp];
    }
    *(f32x4*)&partial[((size_t)blockIdx.x*4 + grp)*DD + dcol*4] = a0;
  }
}

// ---------------- finish: majority vote + select/reduce partials -----------
__global__ __launch_bounds__(256) void finish_kernel(const int* __restrict__ amax,
    const float* __restrict__ partial, const int* __restrict__ mask,
    float* __restrict__ out) {
  __shared__ int cnt[4];
  __shared__ int vsh;
  int bb = blockIdx.x, t = threadIdx.x;
  if (t < 4) cnt[t] = 0;
  __syncthreads();
  int m = mask[bb];
  int c0=0, c1=0, c2=0, c3=0;
  for (int n = t; n < NN; n += 256) {
    if (n < m) {
      int a = amax[bb*NN + n];
      c0 += (a==0); c1 += (a==1); c2 += (a==2); c3 += (a==3);
    }
  }
  atomicAdd(&cnt[0], c0); atomicAdd(&cnt[1], c1);
  atomicAdd(&cnt[2], c2); atomicAdd(&cnt[3], c3);
  __syncthreads();
  if (t == 0) {
    int arg = 0, best = cnt[0];
    if (cnt[1] > best) { best = cnt[1]; arg = 1; }
    if (cnt[2] > best) { best = cnt[2]; arg = 2; }
    if (cnt[3] > best) { best = cnt[3]; arg = 3; }
    vsh = arg;
  }
  __syncthreads();
  int v = vsh;
  for (int d = t; d < DD; d += 256) {
    float f = 0.f;
#pragma unroll
    for (int c = 0; c < BPB; ++c)
      f += partial[(((size_t)(bb*BPB + c))*4 + v)*DD + d];
    out[bb*DD + d] = f;
  }
}

extern "C" void kernel_launch(void* const* d_in, const int* in_sizes, int n_in,
                              void* d_out, int out_size, void* d_ws, size_t ws_size,
                              hipStream_t stream) {
  const float* x    = (const float*)d_in[0];
  const int*   mask = (const int*)d_in[1];
  const float* sub  = (const float*)d_in[2];
  float* out = (float*)d_out;

  float* partial = (float*)d_ws;                         // 512*4*512 f32 = 4 MB
  int*   amax    = (int*)(partial + (size_t)NBLK*4*DD);  // 32768 ints
  unsigned short* subhi = (unsigned short*)(amax + NT);  // 131072 u16
  unsigned short* sublo = subhi + OUTC*DD;
  unsigned short* Ghi   = sublo + OUTC*DD;               // 16384 u16
  unsigned short* Glo   = Ghi + SS*RR*RR;

  // SCALE = 1.718*exp(-count/30000) - 0.718, count = B = 32
  double scale = 1.718 * exp(-((double)BB) / 30000.0) - 0.718;
  float inv_denom = (float)(1.0 / ((double)DD * scale));

  prep_kernel<<<128 + SS, 256, 0, stream>>>(sub, subhi, sublo, Ghi, Glo);
  fused_kernel<<<NBLK, 512, 0, stream>>>(x, subhi, sublo, Ghi, Glo, inv_denom, amax, partial);
  finish_kernel<<<BB, 256, 0, stream>>>(amax, partial, mask, out);
}

// Round 7
// 76.188 us; speedup vs baseline: 1.4243x; 1.0430x over previous
//
#include <hip/hip_runtime.h>
#include <math.h>

#define BB 32
#define NN 1024
#define DD 512
#define SS 4
#define RR 64
#define OUTC 256          // SS*RR
#define NT (BB*NN)        // 32768 tokens
#define MT 64             // tokens per fused block
#define NBLK (NT/MT)      // 512
#define BPB (NN/MT)       // blocks per batch = 16

typedef float4 f4;
typedef float f32x4 __attribute__((ext_vector_type(4)));
typedef __bf16 bf16x8 __attribute__((ext_vector_type(8)));
typedef unsigned short u16x8 __attribute__((ext_vector_type(8)));
typedef const __attribute__((address_space(1))) void GVoid;
typedef __attribute__((address_space(3))) void LVoid;

union BF8 { u16x8 u; bf16x8 b; unsigned w[4]; };

__device__ __forceinline__ float hif(float f) {
  return __uint_as_float(__float_as_uint(f) & 0xffff0000u);
}
__device__ __forceinline__ unsigned short topu(float f) {
  return (unsigned short)(__float_as_uint(f) >> 16);
}
// identity-order pack: (bf16(e0), bf16(e1)) -> u32 (e0 in low half)
__device__ __forceinline__ unsigned pack2(float e0, float e1) {
  return __builtin_amdgcn_perm(__float_as_uint(e1), __float_as_uint(e0), 0x07060302u);
}

#define MFMA(a,b,c) __builtin_amdgcn_mfma_f32_16x16x32_bf16((a),(b),(c),0,0,0)

// lgkm-only barrier: LDS ops visible across waves; in-flight vmcnt loads survive.
#define BARRIER_LGKM() do { \
  asm volatile("s_waitcnt lgkmcnt(0)" ::: "memory"); \
  __builtin_amdgcn_s_barrier(); \
} while (0)
#define WAITV(N) asm volatile("s_waitcnt vmcnt(" #N ")" ::: "memory")

// ---------------- prep: sub -> bf16 hi/lo; Gram G_s = S_s S_s^T -> bf16 hi/lo
__global__ __launch_bounds__(256) void prep_kernel(const float* __restrict__ sub,
    unsigned short* __restrict__ subhi, unsigned short* __restrict__ sublo,
    unsigned short* __restrict__ Ghi, unsigned short* __restrict__ Glo) {
  int t = threadIdx.x, blk = blockIdx.x;
  __shared__ __align__(16) float Sl[64][36];
  if (blk < 128) {
    int i = (blk*256 + t)*4;                   // 128*256*4 = OUTC*DD
    f4 v = *(const f4*)&sub[i];
    uint2 hh, ll;
    hh.x = pack2(v.x, v.y); hh.y = pack2(v.z, v.w);
    ll.x = pack2(v.x - hif(v.x), v.y - hif(v.y));
    ll.y = pack2(v.z - hif(v.z), v.w - hif(v.w));
    *(uint2*)&subhi[i] = hh;
    *(uint2*)&sublo[i] = ll;
    return;
  }
  int s = blk - 128;
  int lane = t & 63, w = t >> 6, l15 = lane & 15, l4 = lane >> 4;
  int row = t >> 2, seg = t & 3;               // staging: 64 rows x 4 segs of 8
  f4 r0, r1;
  f32x4 acc[4] = {{0,0,0,0},{0,0,0,0},{0,0,0,0},{0,0,0,0}};
  {
    const float* p = &sub[(size_t)(s*RR + row)*DD + seg*8];
    r0 = *(const f4*)p; r1 = *(const f4*)(p+4);
  }
  for (int kc = 0; kc < 16; ++kc) {
    __syncthreads();
    *(f4*)&Sl[row][seg*8]   = r0;
    *(f4*)&Sl[row][seg*8+4] = r1;
    __syncthreads();
    if (kc < 15) {
      const float* p = &sub[(size_t)(s*RR + row)*DD + (kc+1)*32 + seg*8];
      r0 = *(const f4*)p; r1 = *(const f4*)(p+4);
    }
    BF8 ah, al;
    {
      int ra = w*16 + l15;
      f32x4 v0 = *(const f32x4*)&Sl[ra][l4*8];
      f32x4 v1 = *(const f32x4*)&Sl[ra][l4*8+4];
      float ff[8] = {v0[0],v0[1],v0[2],v0[3],v1[0],v1[1],v1[2],v1[3]};
#pragma unroll
      for (int e = 0; e < 8; ++e) { ah.u[e] = topu(ff[e]); al.u[e] = topu(ff[e]-hif(ff[e])); }
    }
#pragma unroll
    for (int j = 0; j < 4; ++j) {
      BF8 bh, bl;
      int rb = j*16 + l15;
      f32x4 v0 = *(const f32x4*)&Sl[rb][l4*8];
      f32x4 v1 = *(const f32x4*)&Sl[rb][l4*8+4];
      float ff[8] = {v0[0],v0[1],v0[2],v0[3],v1[0],v1[1],v1[2],v1[3]};
#pragma unroll
      for (int e = 0; e < 8; ++e) { bh.u[e] = topu(ff[e]); bl.u[e] = topu(ff[e]-hif(ff[e])); }
      acc[j] = MFMA(ah.b, bh.b, acc[j]);
      acc[j] = MFMA(ah.b, bl.b, acc[j]);
      acc[j] = MFMA(al.b, bh.b, acc[j]);
    }
  }
#pragma unroll
  for (int j = 0; j < 4; ++j)
#pragma unroll
    for (int r = 0; r < 4; ++r) {
      int grow = w*16 + l4*4 + r, gcol = j*16 + l15;
      float v = acc[j][r];
      Ghi[((size_t)s*RR + grow)*RR + gcol] = topu(v);
      Glo[((size_t)s*RR + grow)*RR + gcol] = topu(v - hif(v));
    }
}

// ---------------- fused: y = x*sub^T (MFMA), q = y^T G y, sparsemax, partials
// 8 waves (512 thr): wave w -> subspace s=w&3, col-half ch=w>>2.
// x staged via global_load_lds DMA (f32, XOR-swizzled source), 4 bufs, 3 deep.
// Conversion to bf16 hi/lo happens in the consumer, fused with fragment reads.
__global__ __launch_bounds__(512, 4) void fused_kernel(
    const float* __restrict__ x,
    const unsigned short* __restrict__ subhi, const unsigned short* __restrict__ sublo,
    const unsigned short* __restrict__ Ghi, const unsigned short* __restrict__ Glo,
    float inv_denom, int* __restrict__ amax, float* __restrict__ partial) {
  __shared__ __align__(16) float stage4[4][2048];   // 32 KB; reused as y scratch
  __shared__ float ssqlds[64];
  __shared__ float prq2[64][4][2];
  __shared__ float Wl[64][4];

  int t = threadIdx.x;
  int lane = t & 63, w = t >> 6;
  int s = w & 3, ch = w >> 2;
  int l15 = lane & 15, l4 = lane >> 4;
  int m0 = blockIdx.x * MT;

  f32x4 acc[4][2] = {};
  float ssq4[4] = {0.f, 0.f, 0.f, 0.f};

  // DMA one 64x32 f32 chunk; thread t -> granule t (linear LDS dest),
  // source seg pre-swizzled so read-side XOR lands on the right data.
  int drow = t >> 3, dsp = t & 7;
  const float* dsrc0 = &x[(size_t)(m0 + drow)*DD + (dsp ^ (drow & 7))*4];
  auto stage = [&](int p) {
    __builtin_amdgcn_global_load_lds((GVoid*)(dsrc0 + p*32),
        (LVoid*)((char*)&stage4[p & 3][0] + t*16), 16, 0, 0);
  };
  auto loadB = [&](BF8 (&bh)[2], BF8 (&bl)[2], int kc) {
#pragma unroll
    for (int nf = 0; nf < 2; ++nf) {
      size_t off = (size_t)(s*64 + ch*32 + nf*16 + l15)*DD + kc*32 + l4*8;
      bh[nf].u = *(const u16x8*)&subhi[off];
      bl[nf].u = *(const u16x8*)&sublo[off];
    }
  };
  auto kstep = [&](int p, BF8 (&bh)[2], BF8 (&bl)[2]) {
    const char* base = (const char*)&stage4[p & 3][0];
#pragma unroll
    for (int mf = 0; mf < 4; ++mf) {
      int row = mf*16 + l15;
      int ph0 = (2*l4) ^ (row & 7), ph1 = (2*l4 + 1) ^ (row & 7);
      f32x4 v0 = *(const f32x4*)(base + row*128 + ph0*16);
      f32x4 v1 = *(const f32x4*)(base + row*128 + ph1*16);
      float f0=v0[0], f1=v0[1], f2=v0[2], f3=v0[3];
      float g4=v1[0], g5=v1[1], g6=v1[2], g7=v1[3];
      if (w == 0)
        ssq4[mf] += f0*f0+f1*f1+f2*f2+f3*f3+g4*g4+g5*g5+g6*g6+g7*g7;
      BF8 ah, al;
      ah.w[0] = pack2(f0,f1); ah.w[1] = pack2(f2,f3);
      ah.w[2] = pack2(g4,g5); ah.w[3] = pack2(g6,g7);
      al.w[0] = pack2(f0-hif(f0), f1-hif(f1));
      al.w[1] = pack2(f2-hif(f2), f3-hif(f3));
      al.w[2] = pack2(g4-hif(g4), g5-hif(g5));
      al.w[3] = pack2(g6-hif(g6), g7-hif(g7));
#pragma unroll
      for (int nf = 0; nf < 2; ++nf) {
        acc[mf][nf] = MFMA(ah.b, bh[nf].b, acc[mf][nf]);
        acc[mf][nf] = MFMA(ah.b, bl[nf].b, acc[mf][nf]);
        acc[mf][nf] = MFMA(al.b, bh[nf].b, acc[mf][nf]);
      }
    }
  };

  BF8 bh[2], bl[2];
  loadB(bh, bl, 0);                 // B0 (oldest in FIFO)
  stage(0); stage(1); stage(2);     // 3-deep DMA prologue
  WAITV(2);                         // s0 landed (own lanes); barrier next
#pragma unroll
  for (int p = 0; p < 16; ++p) {
    BARRIER_LGKM();                 // all waves' stage(p) visible
    if (p + 3 < 16) stage(p + 3);   // overwrites buf (p-1)&3: readers done pre-BAR
    kstep(p, bh, bl);
    if (p + 1 < 16) loadB(bh, bl, p + 1);
    // end-of-phase wait: own stage(p+1) granules landed before next barrier
    if      (p == 0)  WAITV(7);
    else if (p == 1)  WAITV(10);
    else if (p <= 12) WAITV(14);
    else if (p == 13) WAITV(13);
    else if (p == 14) WAITV(12);
    // p == 15: no further consume
  }

  // ssq: wave 0 covered all 64 rows x all k; reduce over l4 groups
  if (w == 0) {
#pragma unroll
    for (int mf = 0; mf < 4; ++mf) {
      float v = ssq4[mf];
      v += __shfl_xor(v, 16); v += __shfl_xor(v, 32);
      if (lane < 16) ssqlds[mf*16 + lane] = v;
    }
  }

  // G fragments (L2-resident); identity-order elements match Ghi scalar layout
  BF8 gh[2][2], gl2[2][2];
#pragma unroll
  for (int kf = 0; kf < 2; ++kf)
#pragma unroll
    for (int nf = 0; nf < 2; ++nf) {
      size_t off = (size_t)(s*RR + (ch*2 + nf)*16 + l15)*RR + kf*32 + l4*8;
      gh[kf][nf].u  = *(const u16x8*)&Ghi[off];
      gl2[kf][nf].u = *(const u16x8*)&Glo[off];
    }
  __syncthreads();   // full drain; stage area becomes y scratch

  float* ysc = &stage4[0][0];       // [s][16][68] f32 = 17408 B
#pragma unroll
  for (int h = 0; h < 4; ++h) {
#pragma unroll
    for (int nf = 0; nf < 2; ++nf)
#pragma unroll
      for (int r = 0; r < 4; ++r)
        ysc[s*1088 + (l4*4 + r)*68 + ch*32 + nf*16 + l15] = acc[h][nf][r];
    __syncthreads();                // ysc[s] complete (both halves)
    BF8 yh[2], yl[2];
#pragma unroll
    for (int kf = 0; kf < 2; ++kf) {
      int base = s*1088 + l15*68 + kf*32 + l4*8;
      f32x4 v0 = *(const f32x4*)&ysc[base];
      f32x4 v1 = *(const f32x4*)&ysc[base+4];
      float ff[8] = {v0[0],v0[1],v0[2],v0[3],v1[0],v1[1],v1[2],v1[3]};
#pragma unroll
      for (int e = 0; e < 8; ++e) {
        yh[kf].u[e] = topu(ff[e]);
        yl[kf].u[e] = topu(ff[e] - hif(ff[e]));
      }
    }
    f32x4 z[2] = {};
#pragma unroll
    for (int nf = 0; nf < 2; ++nf)
#pragma unroll
      for (int kf = 0; kf < 2; ++kf) {
        z[nf] = MFMA(yh[kf].b, gh[kf][nf].b,  z[nf]);
        z[nf] = MFMA(yh[kf].b, gl2[kf][nf].b, z[nf]);
        z[nf] = MFMA(yl[kf].b, gh[kf][nf].b,  z[nf]);
      }
#pragma unroll
    for (int r = 0; r < 4; ++r) {
      float qp = z[0][r]*acc[h][0][r] + z[1][r]*acc[h][1][r];
      qp += __shfl_xor(qp, 1); qp += __shfl_xor(qp, 2);
      qp += __shfl_xor(qp, 4); qp += __shfl_xor(qp, 8);
      if (l15 == 0) prq2[h*16 + l4*4 + r][s][ch] = qp;
    }
    __syncthreads();                // readers done before next h overwrites
  }

  if (t < MT) {
    float ss = ssqlds[t];
    float inv = 1.f / fmaxf(sqrtf(ss), 1e-12f);
    float p0 = sqrtf(fmaxf(prq2[t][0][0] + prq2[t][0][1], 0.f)) * inv * inv_denom;
    float p1 = sqrtf(fmaxf(prq2[t][1][0] + prq2[t][1][1], 0.f)) * inv * inv_denom;
    float p2 = sqrtf(fmaxf(prq2[t][2][0] + prq2[t][2][1], 0.f)) * inv * inv_denom;
    float p3 = sqrtf(fmaxf(prq2[t][3][0] + prq2[t][3][1], 0.f)) * inv * inv_denom;
    float a0=p0, a1=p1, a2=p2, a3=p3, hi, lo;
    hi = fmaxf(a0,a1); lo = fminf(a0,a1); a0=hi; a1=lo;
    hi = fmaxf(a2,a3); lo = fminf(a2,a3); a2=hi; a3=lo;
    hi = fmaxf(a0,a2); lo = fminf(a0,a2); a0=hi; a2=lo;
    hi = fmaxf(a1,a3); lo = fminf(a1,a3); a1=hi; a3=lo;
    hi = fmaxf(a1,a2); lo = fminf(a1,a2); a1=hi; a2=lo;
    float c2 = a0+a1, c3 = c2+a2, c4s = c3+a3;
    int ksup = 1 + (2.f*a1 > c2-1.f) + (3.f*a2 > c3-1.f) + (4.f*a3 > c4s-1.f);
    float csel = (ksup==1) ? a0 : (ksup==2) ? c2 : (ksup==3) ? c3 : c4s;
    float tau = (csel - 1.f) / (float)ksup;
    float q0 = fmaxf(p0-tau, 0.f), q1 = fmaxf(p1-tau, 0.f);
    float q2 = fmaxf(p2-tau, 0.f), q3 = fmaxf(p3-tau, 0.f);
    int arg = 0; float best = q0;
    if (q1 > best) { best = q1; arg = 1; }
    if (q2 > best) { best = q2; arg = 2; }
    if (q3 > best) { best = q3; arg = 3; }
    amax[m0 + t] = arg;
    Wl[t][0] = q0*inv; Wl[t][1] = q1*inv; Wl[t][2] = q2*inv; Wl[t][3] = q3*inv;
  }
  __syncthreads();

  // per-subspace feature partials over this block's 64 tokens (x re-read ~L2)
  {
    int grp = t >> 7, dcol = t & 127;      // grp = subspace, 128 dcols of f32x4
    f32x4 a0 = {0,0,0,0};
#pragma unroll 8
    for (int tok = 0; tok < MT; ++tok) {
      f32x4 v = *(const f32x4*)&x[(size_t)(m0 + tok)*DD + dcol*4];
      a0 += v * Wl[tok][grp];
    }
    *(f32x4*)&partial[((size_t)blockIdx.x*4 + grp)*DD + dcol*4] = a0;
  }
}

// ---------------- finish: majority vote + select/reduce partials -----------
__global__ __launch_bounds__(256) void finish_kernel(const int* __restrict__ amax,
    const float* __restrict__ partial, const int* __restrict__ mask,
    float* __restrict__ out) {
  __shared__ int cnt[4];
  __shared__ int vsh;
  int bb = blockIdx.x, t = threadIdx.x;
  if (t < 4) cnt[t] = 0;
  __syncthreads();
  int m = mask[bb];
  int c0=0, c1=0, c2=0, c3=0;
  for (int n = t; n < NN; n += 256) {
    if (n < m) {
      int a = amax[bb*NN + n];
      c0 += (a==0); c1 += (a==1); c2 += (a==2); c3 += (a==3);
    }
  }
  atomicAdd(&cnt[0], c0); atomicAdd(&cnt[1], c1);
  atomicAdd(&cnt[2], c2); atomicAdd(&cnt[3], c3);
  __syncthreads();
  if (t == 0) {
    int arg = 0, best = cnt[0];
    if (cnt[1] > best) { best = cnt[1]; arg = 1; }
    if (cnt[2] > best) { best = cnt[2]; arg = 2; }
    if (cnt[3] > best) { best = cnt[3]; arg = 3; }
    vsh = arg;
  }
  __syncthreads();
  int v = vsh;
  for (int d = t; d < DD; d += 256) {
    float f = 0.f;
#pragma unroll
    for (int c = 0; c < BPB; ++c)
      f += partial[(((size_t)(bb*BPB + c))*4 + v)*DD + d];
    out[bb*DD + d] = f;
  }
}

extern "C" void kernel_launch(void* const* d_in, const int* in_sizes, int n_in,
                              void* d_out, int out_size, void* d_ws, size_t ws_size,
                              hipStream_t stream) {
  const float* x    = (const float*)d_in[0];
  const int*   mask = (const int*)d_in[1];
  const float* sub  = (const float*)d_in[2];
  float* out = (float*)d_out;

  float* partial = (float*)d_ws;                         // 512*4*512 f32 = 4 MB
  int*   amax    = (int*)(partial + (size_t)NBLK*4*DD);  // 32768 ints
  unsigned short* subhi = (unsigned short*)(amax + NT);  // 131072 u16
  unsigned short* sublo = subhi + OUTC*DD;
  unsigned short* Ghi   = sublo + OUTC*DD;               // 16384 u16
  unsigned short* Glo   = Ghi + SS*RR*RR;

  // SCALE = 1.718*exp(-count/30000) - 0.718, count = B = 32
  double scale = 1.718 * exp(-((double)BB) / 30000.0) - 0.718;
  float inv_denom = (float)(1.0 / ((double)DD * scale));

  prep_kernel<<<128 + SS, 256, 0, stream>>>(sub, subhi, sublo, Ghi, Glo);
  fused_kernel<<<NBLK, 512, 0, stream>>>(x, subhi, sublo, Ghi, Glo, inv_denom, amax, partial);
  finish_kernel<<<BB, 256, 0, stream>>>(amax, partial, mask, out);
}